// Round 1
// baseline (274.247 us; speedup 1.0000x reference)
//
#include <hip/hip_runtime.h>

// TileWarping: B=4, C=16, H=512, W=960, UP=4, h=128, w=240
// out: [B, 48, h, w] float32; 48 = 3 disp_d x (UP*UP)
//
// Structure: one block per (Y, b) row; thread t < 240 owns x-tile t
// (full-res X = 4t..4t+3). Per channel-chunk of 4, stage fea_r rows into
// LDS with swizzle sidx(x) = x + (x>>5) (kills the stride-4 8-way bank
// conflict -> 2 lanes/bank, free on wave64), then 24 LDS gathers/channel.
// fea_l read once per pixel (shared across the 3 disp_d variants).

#define UPF 4
#define NB 4
#define NC 16
#define NH 512
#define NW 960
#define TH 128
#define TW 240
#define CHUNK 4
#define LDSROW 992   // swizzled span: 959 + (959>>5)=988, pad to 992

__global__ __launch_bounds__(256) void tile_warp_kernel(
    const float* __restrict__ tp,   // [B,3,h,w]
    const float* __restrict__ fl,   // [B,C,H,W]
    const float* __restrict__ fr,   // [B,C,H,W]
    float* __restrict__ out)        // [B,48,h,w]
{
    const int Y = blockIdx.x;       // 0..511
    const int b = blockIdx.y;       // 0..3
    const int t = threadIdx.x;      // 0..255 (240 active)
    const int y = Y >> 2;
    const int i = Y & 3;

    __shared__ float lds[CHUNK * LDSROW];

    float w0v[12], w1v[12], acc[12];
    int   s0[12],  s1[12];

    const bool active = (t < TW);

    if (active) {
        const int tpbase = (b * 3 * TH + y) * TW + t;
        const float d  = tp[tpbase];
        const float dx = tp[tpbase + TH * TW];
        const float dy = tp[tpbase + 2 * TH * TW];
        const float offi = (float)i - 1.5f;
        const float base = d + offi * dy;
#pragma unroll
        for (int k = 0; k < 3; ++k) {
#pragma unroll
            for (int j = 0; j < 4; ++j) {
                const int idx = k * 4 + j;
                const float offj = (float)j - 1.5f;
                const float disp = base + (float)(k - 1) + offj * dx;
                const float xf = (float)(4 * t + j) - disp;
                const float x0f = floorf(xf);
                const float w1 = xf - x0f;
                const float w0 = 1.0f - w1;
                const int x0 = (int)x0f;
                const int x1 = x0 + 1;
                w0v[idx] = (x0 >= 0 && x0 < NW) ? w0 : 0.0f;
                w1v[idx] = (x1 >= 0 && x1 < NW) ? w1 : 0.0f;
                const int x0c = min(max(x0, 0), NW - 1);
                const int x1c = min(max(x1, 0), NW - 1);
                s0[idx] = x0c + (x0c >> 5);
                s1[idx] = x1c + (x1c >> 5);
                acc[idx] = 0.0f;
            }
        }
    }

    for (int c0 = 0; c0 < NC; c0 += CHUNK) {
        __syncthreads();   // protect LDS from previous chunk's readers
        if (active) {
#pragma unroll
            for (int cc = 0; cc < CHUNK; ++cc) {
                const float* row = fr + ((size_t)((b * NC + c0 + cc) * NH + Y)) * NW;
                const float4 v = ((const float4*)row)[t];
                const int xb = 4 * t;
                float* l = lds + cc * LDSROW + xb + (xb >> 5);
                l[0] = v.x; l[1] = v.y; l[2] = v.z; l[3] = v.w;
            }
        }
        __syncthreads();
        if (active) {
#pragma unroll
            for (int cc = 0; cc < CHUNK; ++cc) {
                const float* lrow = fl + ((size_t)((b * NC + c0 + cc) * NH + Y)) * NW;
                const float4 fv = ((const float4*)lrow)[t];
                const float flv[4] = {fv.x, fv.y, fv.z, fv.w};
                const float* __restrict__ L = lds + cc * LDSROW;
#pragma unroll
                for (int k = 0; k < 3; ++k) {
#pragma unroll
                    for (int j = 0; j < 4; ++j) {
                        const int idx = k * 4 + j;
                        const float g0 = L[s0[idx]];
                        const float g1 = L[s1[idx]];
                        const float wv = g0 * w0v[idx] + g1 * w1v[idx];
                        acc[idx] += fabsf(flv[j] - wv);
                    }
                }
            }
        }
    }

    if (active) {
#pragma unroll
        for (int k = 0; k < 3; ++k) {
#pragma unroll
            for (int j = 0; j < 4; ++j) {
                const int ch = k * 16 + i * 4 + j;
                out[((size_t)(b * 48 + ch) * TH + y) * TW + t] = acc[k * 4 + j];
            }
        }
    }
}

extern "C" void kernel_launch(void* const* d_in, const int* in_sizes, int n_in,
                              void* d_out, int out_size, void* d_ws, size_t ws_size,
                              hipStream_t stream) {
    const float* tp = (const float*)d_in[0];   // tile_plane [4,3,128,240]
    const float* fl = (const float*)d_in[1];   // fea_l [4,16,512,960]
    const float* fr = (const float*)d_in[2];   // fea_r [4,16,512,960]
    float* out = (float*)d_out;                // [4,48,128,240]

    dim3 grid(NH, NB);   // (512, 4)
    dim3 block(256);
    tile_warp_kernel<<<grid, block, 0, stream>>>(tp, fl, fr, out);
}

// Round 2
// 272.149 us; speedup vs baseline: 1.0077x; 1.0077x over previous
//
#include <hip/hip_runtime.h>

// TileWarping: B=4, C=16, H=512, W=960, UP=4 -> out [4, 48, 128, 240] f32.
// R1 design:
//  - block = one (Y,b) full-res row, 960 threads (15 waves), thread u <-> X=u
//    (tile T=u>>2, up-phase j=u&3). Gather addresses ~= u + jitter -> stride-1
//    LDS access, no swizzle needed.
//  - k-trick: the 3 disp_d variants share fractional weights; all 6 bilinear
//    taps live in L[x0-1 .. x0+2] -> 4 consecutive LDS reads (ds_read2_b32 x2).
//    Out-of-range handled by zero-masking the per-variant WEIGHTS (channel-
//    invariant), so guard-zone reads may return garbage safely.
//  - fea_r row staged via async global_load_lds width=16 into a flat
//    contiguous LDS image (guards at both ends); chunk1 DMA overlaps chunk0
//    compute; exactly 2 barriers.

#define NB 4
#define NC 16
#define NH 512
#define NW 960
#define TH 128
#define TW 240
#define HW (NH * NW)
#define GUARD 16
#define CHUNK 8                       // channels per chunk
#define CBUF (2 * GUARD + CHUNK * NW) // 7712 floats per chunk buffer

typedef const __attribute__((address_space(1))) unsigned int* gas_u32;
typedef __attribute__((address_space(3))) unsigned int* las_u32;

__device__ __forceinline__ void stage16(const float* g, float* l) {
    __builtin_amdgcn_global_load_lds((gas_u32)g, (las_u32)l, 16, 0, 0);
}

__global__ __launch_bounds__(960, 8) void tile_warp_kernel(
    const float* __restrict__ tp,   // [B,3,128,240]
    const float* __restrict__ fl,   // [B,16,512,960]
    const float* __restrict__ fr,   // [B,16,512,960]
    float* __restrict__ out)        // [B,48,128,240]
{
    const int u = threadIdx.x;      // global X, 0..959
    const int Y = blockIdx.x;       // 0..511
    const int b = blockIdx.y;       // 0..3
    const int y = Y >> 2, i = Y & 3;
    const int T = u >> 2, j = u & 3;

    __shared__ float smem[2][CBUF];

    const float* frrow = fr + (size_t)(b * NC) * HW + (size_t)Y * NW;
    const float* flrow = fl + (size_t)(b * NC) * HW + (size_t)Y * NW + u;

    // ---- stage chunk 0 (channels 0..7), async DMA, width 16 ----
    {
        const int s0 = u, s1 = u + 960;           // 16B slots over 8x960 dwords
        stage16(frrow + (s0 / 240) * HW + 4 * (s0 % 240), &smem[0][GUARD + 4 * s0]);
        stage16(frrow + (s1 / 240) * HW + 4 * (s1 % 240), &smem[0][GUARD + 4 * s1]);
    }

    // ---- per-thread setup ----
    const int tpb = (b * 3 * TH + y) * TW + T;
    const float d   = tp[tpb];
    const float dxv = tp[tpb + TH * TW];
    const float dyv = tp[tpb + 2 * TH * TW];
    const float base = d + ((float)i - 1.5f) * dyv + ((float)j - 1.5f) * dxv;
    const float xf  = (float)u - base;            // kk=1 (disp_d = 0)
    const float x0f = floorf(xf);
    const float w1  = xf - x0f;
    const float w0  = 1.0f - w1;
    const int   x0  = (int)x0f;
    const int   p   = x0 - 1;                     // taps at x = p .. p+3
    const int   p_cl = max(min(p, NW + 12), -GUARD);

    // per-variant masked weights: wv_kk = m[2-kk]*w0k[kk] + m[3-kk]*w1k[kk]
    float w0k[3], w1k[3];
#pragma unroll
    for (int kk = 0; kk < 3; ++kk) {
        const int xa = p + 2 - kk;                // g0 tap
        const int xb = p + 3 - kk;                // g1 tap
        w0k[kk] = (xa >= 0 && xa < NW) ? w0 : 0.0f;
        w1k[kk] = (xb >= 0 && xb < NW) ? w1 : 0.0f;
    }
    float acc0 = 0.f, acc1 = 0.f, acc2 = 0.f;

    __syncthreads();                              // chunk0 DMA drained

    // ---- stage chunk 1 async: overlaps with compute of chunk 0 ----
    {
        const float* frrow1 = frrow + CHUNK * HW;
        const int s0 = u, s1 = u + 960;
        stage16(frrow1 + (s0 / 240) * HW + 4 * (s0 % 240), &smem[1][GUARD + 4 * s0]);
        stage16(frrow1 + (s1 / 240) * HW + 4 * (s1 % 240), &smem[1][GUARD + 4 * s1]);
    }

    // ---- compute chunk 0 ----
    {
        float flv[CHUNK];
#pragma unroll
        for (int c = 0; c < CHUNK; ++c) flv[c] = flrow[c * HW];
#pragma unroll
        for (int c = 0; c < CHUNK; ++c) {
            const float* L = &smem[0][GUARD + c * NW + p_cl];
            const float m0 = L[0], m1 = L[1], m2 = L[2], m3 = L[3];
            const float wv0 = m2 * w0k[0] + m3 * w1k[0];
            const float wv1 = m1 * w0k[1] + m2 * w1k[1];
            const float wv2 = m0 * w0k[2] + m1 * w1k[2];
            acc0 += fabsf(flv[c] - wv0);
            acc1 += fabsf(flv[c] - wv1);
            acc2 += fabsf(flv[c] - wv2);
        }
    }

    __syncthreads();                              // chunk1 DMA drained

    // ---- compute chunk 1 ----
    {
        float flv[CHUNK];
#pragma unroll
        for (int c = 0; c < CHUNK; ++c) flv[c] = flrow[(CHUNK + c) * HW];
#pragma unroll
        for (int c = 0; c < CHUNK; ++c) {
            const float* L = &smem[1][GUARD + c * NW + p_cl];
            const float m0 = L[0], m1 = L[1], m2 = L[2], m3 = L[3];
            const float wv0 = m2 * w0k[0] + m3 * w1k[0];
            const float wv1 = m1 * w0k[1] + m2 * w1k[1];
            const float wv2 = m0 * w0k[2] + m1 * w1k[2];
            acc0 += fabsf(flv[c] - wv0);
            acc1 += fabsf(flv[c] - wv1);
            acc2 += fabsf(flv[c] - wv2);
        }
    }

    // ---- store: ch = kk*16 + i*4 + j ----
    const size_t obase = ((size_t)(b * 48 + i * 4 + j) * TH + y) * TW + T;
    out[obase]                        = acc0;
    out[obase + 16 * (size_t)TH * TW] = acc1;
    out[obase + 32 * (size_t)TH * TW] = acc2;
}

extern "C" void kernel_launch(void* const* d_in, const int* in_sizes, int n_in,
                              void* d_out, int out_size, void* d_ws, size_t ws_size,
                              hipStream_t stream) {
    const float* tp = (const float*)d_in[0];
    const float* fl = (const float*)d_in[1];
    const float* fr = (const float*)d_in[2];
    float* out = (float*)d_out;

    dim3 grid(NH, NB);   // (512, 4)
    dim3 block(960);     // 15 waves, thread u == column X
    tile_warp_kernel<<<grid, block, 0, stream>>>(tp, fl, fr, out);
}